// Round 1
// baseline (331.033 us; speedup 1.0000x reference)
//
#include <hip/hip_runtime.h>

// Dense 2D spatial transformer (bilinear warp with dense flow), 4096x4096, f32.
//
// Reference semantics replicated exactly:
//   H_up = (flow_h + h) + 1.0   (note grouping: flow+mesh first, then +1)
//   W_up = (flow_w + w) + 1.0
//   hf = floor(H_up); hc = hf+1; clamp each to [0, Hp-1] with Hp = H+2
//   dH = (float)hc_clamped - H_up ; dW = (float)wc_clamped - W_up
//   sample zero-padded image at clamped padded coords
//   out = v00*dW*dH + v10*dW*(1-dH) + v01*(1-dW)*dH + v11*(1-dW)*(1-dH)

#define IMG_H 4096
#define IMG_W 4096

__global__ __launch_bounds__(256) void warp_bilinear_kernel(
    const float* __restrict__ img,   // [H, W]
    const float* __restrict__ flow,  // [2, H, W]: plane 0 = dH, plane 1 = dW
    float* __restrict__ out)         // [H, W]
{
    const int HW = IMG_H * IMG_W;
    int t = blockIdx.x * blockDim.x + threadIdx.x;
    int base = t * 4;
    if (base >= HW) return;

    const float4 fh4 = *reinterpret_cast<const float4*>(flow + base);
    const float4 fw4 = *reinterpret_cast<const float4*>(flow + HW + base);

    const int h  = base >> 12;          // / 4096
    const int w0 = base & (IMG_W - 1);  // % 4096 (4 pixels stay in one row)

    const float fh[4] = {fh4.x, fh4.y, fh4.z, fh4.w};
    const float fw[4] = {fw4.x, fw4.y, fw4.z, fw4.w};
    float res[4];

    #pragma unroll
    for (int i = 0; i < 4; ++i) {
        // Match reference float-add grouping exactly: (flow + mesh) + 1.0
        float Hu = (fh[i] + (float)h) + 1.0f;
        float Wu = (fw[i] + (float)(w0 + i)) + 1.0f;

        int hf = (int)floorf(Hu);
        int wf = (int)floorf(Wu);
        int hc = hf + 1;
        int wc = wf + 1;

        // clamp to padded range [0, H+1] / [0, W+1]
        int hfc = min(max(hf, 0), IMG_H + 1);
        int hcc = min(max(hc, 0), IMG_H + 1);
        int wfc = min(max(wf, 0), IMG_W + 1);
        int wcc = min(max(wc, 0), IMG_W + 1);

        // weights use CLAMPED hc/wc (reference clips before computing dH/dW)
        float dH = (float)hcc - Hu;
        float dW = (float)wcc - Wu;

        // padded image sample: pad index p maps to img[p-1]; border -> 0
        bool hf_in = (hfc >= 1) && (hfc <= IMG_H);
        bool hc_in = (hcc >= 1) && (hcc <= IMG_H);
        bool wf_in = (wfc >= 1) && (wfc <= IMG_W);
        bool wc_in = (wcc >= 1) && (wcc <= IMG_W);

        long rowf = (long)(hfc - 1) * IMG_W;
        long rowc = (long)(hcc - 1) * IMG_W;

        float v00 = (hf_in && wf_in) ? img[rowf + (wfc - 1)] : 0.0f;
        float v10 = (hc_in && wf_in) ? img[rowc + (wfc - 1)] : 0.0f;
        float v01 = (hf_in && wc_in) ? img[rowf + (wcc - 1)] : 0.0f;
        float v11 = (hc_in && wc_in) ? img[rowc + (wcc - 1)] : 0.0f;

        res[i] = v00 * (dW * dH)
               + v10 * (dW * (1.0f - dH))
               + v01 * ((1.0f - dW) * dH)
               + v11 * ((1.0f - dW) * (1.0f - dH));
    }

    *reinterpret_cast<float4*>(out + base) = make_float4(res[0], res[1], res[2], res[3]);
}

extern "C" void kernel_launch(void* const* d_in, const int* in_sizes, int n_in,
                              void* d_out, int out_size, void* d_ws, size_t ws_size,
                              hipStream_t stream) {
    const float* img  = (const float*)d_in[0];   // [1,1,4096,4096]
    const float* flow = (const float*)d_in[1];   // [1,2,4096,4096]
    float* out = (float*)d_out;                  // [1,1,4096,4096]

    const int HW = IMG_H * IMG_W;
    const int threads = 256;
    const int blocks = (HW / 4 + threads - 1) / threads;  // 16384
    warp_bilinear_kernel<<<blocks, threads, 0, stream>>>(img, flow, out);
}

// Round 2
// 265.470 us; speedup vs baseline: 1.2470x; 1.2470x over previous
//
#include <hip/hip_runtime.h>

// Dense 2D spatial transformer (bilinear warp with dense flow), 4096x4096, f32.
//
// Round 2: gather-coalescing layout. 1 pixel per thread; block = 4 rows x 64
// cols tile (one wave per row). Each gather instruction's 64 lanes sample 64
// horizontally-consecutive pixels (+-N(0,1) jitter) -> ~5-7 cache lines per
// wave gather instead of ~20 with the round-1 "4 consecutive px/thread"
// layout (16B lane stride). Vertical tap overlap (v10 of row r == v00 of
// row r+1) now hits in L1 within the block.
//
// Reference semantics replicated exactly (same math as the passing R1 kernel):
//   H_up = (flow_h + h) + 1.0 ; W_up = (flow_w + w) + 1.0
//   hf = floor(H_up); hc = hf+1; clamp each to [0, H+1] (padded dims)
//   dH = (float)hc_clamped - H_up ; dW = (float)wc_clamped - W_up
//   zero-padded sample at clamped padded coords; bilinear blend.

#define IMG_H 4096
#define IMG_W 4096

__global__ __launch_bounds__(256) void warp_bilinear_kernel(
    const float* __restrict__ img,   // [H, W]
    const float* __restrict__ flow,  // [2, H, W]: plane 0 = dH, plane 1 = dW
    float* __restrict__ out)         // [H, W]
{
    const int HW = IMG_H * IMG_W;
    const int lane = threadIdx.x & 63;
    const int wv   = threadIdx.x >> 6;           // 0..3 (wave id = row in tile)
    const int h = blockIdx.y * 4 + wv;           // gridDim.y = 1024
    const int w = blockIdx.x * 64 + lane;        // gridDim.x = 64
    const int idx = h * IMG_W + w;

    const float fh = flow[idx];
    const float fw = flow[HW + idx];

    // Match reference float-add grouping exactly: (flow + mesh) + 1.0
    float Hu = (fh + (float)h) + 1.0f;
    float Wu = (fw + (float)w) + 1.0f;

    int hf = (int)floorf(Hu);
    int wf = (int)floorf(Wu);
    int hc = hf + 1;
    int wc = wf + 1;

    // clamp to padded range [0, H+1] / [0, W+1]
    int hfc = min(max(hf, 0), IMG_H + 1);
    int hcc = min(max(hc, 0), IMG_H + 1);
    int wfc = min(max(wf, 0), IMG_W + 1);
    int wcc = min(max(wc, 0), IMG_W + 1);

    // weights use CLAMPED hc/wc (reference clips before computing dH/dW)
    float dH = (float)hcc - Hu;
    float dW = (float)wcc - Wu;

    // padded image sample: pad index p maps to img[p-1]; border -> 0
    bool hf_in = (hfc >= 1) && (hfc <= IMG_H);
    bool hc_in = (hcc >= 1) && (hcc <= IMG_H);
    bool wf_in = (wfc >= 1) && (wfc <= IMG_W);
    bool wc_in = (wcc >= 1) && (wcc <= IMG_W);

    long rowf = (long)(hfc - 1) * IMG_W;
    long rowc = (long)(hcc - 1) * IMG_W;

    float v00 = (hf_in && wf_in) ? img[rowf + (wfc - 1)] : 0.0f;
    float v10 = (hc_in && wf_in) ? img[rowc + (wfc - 1)] : 0.0f;
    float v01 = (hf_in && wc_in) ? img[rowf + (wcc - 1)] : 0.0f;
    float v11 = (hc_in && wc_in) ? img[rowc + (wcc - 1)] : 0.0f;

    float res = v00 * (dW * dH)
              + v10 * (dW * (1.0f - dH))
              + v01 * ((1.0f - dW) * dH)
              + v11 * ((1.0f - dW) * (1.0f - dH));

    out[idx] = res;
}

extern "C" void kernel_launch(void* const* d_in, const int* in_sizes, int n_in,
                              void* d_out, int out_size, void* d_ws, size_t ws_size,
                              hipStream_t stream) {
    const float* img  = (const float*)d_in[0];   // [1,1,4096,4096]
    const float* flow = (const float*)d_in[1];   // [1,2,4096,4096]
    float* out = (float*)d_out;                  // [1,1,4096,4096]

    dim3 grid(IMG_W / 64, IMG_H / 4);            // (64, 1024)
    dim3 block(256);
    warp_bilinear_kernel<<<grid, block, 0, stream>>>(img, flow, out);
}